// Round 13
// baseline (3249.130 us; speedup 1.0000x reference)
//
#include <hip/hip_runtime.h>
#include <hip/hip_bf16.h>
#include <stdint.h>

// LSTM: T=512, B=64, D=1024, H=1024, gates order i,f,g,o
#define T_STEPS 512
#define BATCH   64
#define DIM     1024
#define HID     1024
#define NG      4096                 // 4*HID
#define MROWS   (T_STEPS * BATCH)    // 32768

typedef __bf16 bf16;
typedef __bf16 bf16x4 __attribute__((ext_vector_type(4)));
typedef __bf16 bf16x8 __attribute__((ext_vector_type(8)));
typedef float  f32x4  __attribute__((ext_vector_type(4)));
typedef unsigned int u32;
typedef u32 u32x2 __attribute__((ext_vector_type(2)));
typedef u32 u32x4 __attribute__((ext_vector_type(4)));

__device__ __forceinline__ void g2lds16(const void* g, void* l) {
    __builtin_amdgcn_global_load_lds(
        (const __attribute__((address_space(1))) void*)g,
        (__attribute__((address_space(3))) void*)l, 16, 0, 0);
}

__device__ __forceinline__ float fsigmoid(float x) {
    return 1.0f / (1.0f + __expf(-x));   // safe at +-inf
}
__device__ __forceinline__ float ftanh_(float x) {
    return 1.0f - 2.0f / (__expf(2.0f * x) + 1.0f);   // safe at +-inf
}

// ---- LLC-coherent (bypass L1+L2) ops: proven R2-R12 ----
__device__ __forceinline__ u32x4 load16_cc(const void* p) {
    u32x4 r;
    asm volatile("global_load_dwordx4 %0, %1, off sc0 sc1" : "=v"(r) : "v"(p) : "memory");
    return r;
}
__device__ __forceinline__ u32x2 load8_cc(const void* p) {
    u32x2 r;
    asm volatile("global_load_dwordx2 %0, %1, off sc0 sc1" : "=v"(r) : "v"(p) : "memory");
    return r;
}
__device__ __forceinline__ void store2_cc(void* p, u32 v) {
    asm volatile("global_store_short %0, %1, off sc0 sc1" :: "v"(p), "v"(v) : "memory");
}
__device__ __forceinline__ void store4_f32(float* p, float v) {
    asm volatile("global_store_dword %0, %1, off" :: "v"(p), "v"(v) : "memory");
}
#define WAITVM(n) asm volatile("s_waitcnt vmcnt(" #n ")" ::: "memory")

// ---------------------------------------------------------------------------
// prep: fp32->bf16 conversions, W_ih column-permute (n' = (n&1023)*4 + (n>>10)),
// W_hh scatter into MFMA-fragment order (wfrag), bias sum (permuted),
// zero h0 buffer, barrier flags, and GEMM row-progress counters
// (all re-zeroed every launch => replay-safe).
// ---------------------------------------------------------------------------
__global__ __launch_bounds__(256) void prep_kernel(
    const float* __restrict__ x,   const float* __restrict__ wih,
    const float* __restrict__ whh, const float* __restrict__ bih,
    const float* __restrict__ bhh,
    bf16* __restrict__ xb, bf16* __restrict__ wihp, bf16* __restrict__ wfrag,
    float* __restrict__ bsump, bf16* __restrict__ hbuf, u32* __restrict__ flags,
    u32* __restrict__ mrowdone)
{
    const int nt  = gridDim.x * blockDim.x;
    const int gid = blockIdx.x * blockDim.x + threadIdx.x;

    for (int i = gid; i < MROWS * DIM / 4; i += nt) {
        f32x4 v = *(const f32x4*)(x + (size_t)i * 4);
        bf16x4 o = {(bf16)v[0], (bf16)v[1], (bf16)v[2], (bf16)v[3]};
        *(bf16x4*)(xb + (size_t)i * 4) = o;
    }
    for (int i = gid; i < NG * (DIM / 4); i += nt) {
        const int n = i >> 8, c4 = (i & 255) * 4;
        f32x4 v = *(const f32x4*)(wih + (size_t)n * DIM + c4);
        bf16x4 o = {(bf16)v[0], (bf16)v[1], (bf16)v[2], (bf16)v[3]};
        const int np = ((n & 1023) << 2) | (n >> 10);
        *(bf16x4*)(wihp + (size_t)np * DIM + c4) = o;
    }
    // wfrag: element i = ((hg*4 + wv)*64 + f)*64 + lane, f = kk*8+n;
    // grow = (lane&3)*1024 + hg*32 + n*4 + ((lane&15)>>2), k0 = wv*256+kk*32+(lane>>4)*8
    for (int i = gid; i < NG * HID / 8; i += nt) {
        const int lane = i & 63;
        const int f    = (i >> 6) & 63;
        const int wv   = (i >> 12) & 3;
        const int hg   = i >> 14;
        const int n = f & 7, kk = f >> 3;
        const int grow = (lane & 3) * 1024 + hg * 32 + n * 4 + ((lane & 15) >> 2);
        const int k0   = wv * 256 + kk * 32 + (lane >> 4) * 8;
        f32x4 v0 = *(const f32x4*)(whh + (size_t)grow * HID + k0);
        f32x4 v1 = *(const f32x4*)(whh + (size_t)grow * HID + k0 + 4);
        bf16x8 o = {(bf16)v0[0], (bf16)v0[1], (bf16)v0[2], (bf16)v0[3],
                    (bf16)v1[0], (bf16)v1[1], (bf16)v1[2], (bf16)v1[3]};
        *(bf16x8*)(wfrag + (size_t)i * 8) = o;
    }
    for (int i = gid; i < NG; i += nt)
        bsump[((i & 1023) << 2) | (i >> 10)] = bih[i] + bhh[i];
    for (int i = gid; i < BATCH * HID / 4; i += nt) {
        bf16x4 z = {(bf16)0.f, (bf16)0.f, (bf16)0.f, (bf16)0.f};
        *(bf16x4*)(hbuf + (size_t)i * 4) = z;   // h[buf 0] = 0
    }
    for (int i = gid; i < 256 * 16; i += nt)
        flags[i] = 0u;
    for (int i = gid; i < 256; i += nt)
        mrowdone[i] = 0u;
}

// ---------------------------------------------------------------------------
// Fused persistent kernel, 512 WGs x 256 threads, __launch_bounds__(256,2)
// => VGPR<=256 and LDS 33.9KB => 2 WGs/CU co-resident (one of each role).
//
// blocks 0..255  — GEMM role: 32 tiles each of C[32768,4096] = xb@wihp^T+b,
//   tile g = w + round*256 (M-major: rounds produce M-rows 8r..8r+7, i.e.
//   timesteps in increasing order). Epilogue stores write-through (sc0 sc1),
//   then vmcnt(0) + syncthreads + atomicAdd(mrowdone[by]) — release.
//   No dependence on the LSTM role => even without co-residency the GEMM
//   drains fully and the LSTM then runs sequentially (graceful fallback).
//
// blocks 256..511 — LSTM role: R12 kernel verbatim, except (a) xg loads use
//   sc0 sc1 (always LLC-fresh, slack-covered), (b) the A1 poll additionally
//   gates on mrowdone[(t+1)>>1] >= 32 before the E-phase xg prefetch target.
// ---------------------------------------------------------------------------
__global__ __launch_bounds__(256, 2) void fused_kernel(
    const bf16* __restrict__ xb, const bf16* __restrict__ wihp,
    const float* __restrict__ bsum, bf16* __restrict__ xgp,
    const bf16* __restrict__ wfrag, bf16* __restrict__ hbuf,
    u32* __restrict__ flags, u32* __restrict__ mrowdone,
    float* __restrict__ out)
{
    __shared__ __align__(16) char smem[33920];
    const int tid  = threadIdx.x;
    const int lane = tid & 63;
    const int wv   = tid >> 6;

    if (blockIdx.x < 256) {
        // ================= GEMM role =================
        char* As = smem;
        char* Bs = smem + 8192;
        const int wr = wv >> 1, wc = wv & 1;
        const int r4 = tid >> 2;
        const int c8 = (tid & 3) * 8;
        const int ldsoff = tid * 16;

        for (int tno = 0; tno < 32; ++tno) {
            const int g  = (int)blockIdx.x + tno * 256;
            const int bx = g & 31, by = g >> 5;
            const int m0 = by * 128, n0 = bx * 128;
            const size_t arow0 = (size_t)(m0 +      r4) * DIM + c8;
            const size_t arow1 = (size_t)(m0 + 64 + r4) * DIM + c8;
            const size_t brow0 = (size_t)(n0 +      r4) * DIM + c8;
            const size_t brow1 = (size_t)(n0 + 64 + r4) * DIM + c8;

            f32x4 acc[4][4] = {};
            for (int k0 = 0; k0 < DIM; k0 += 32) {
                g2lds16(xb   + arow0 + k0, As + ldsoff);
                g2lds16(xb   + arow1 + k0, As + 4096 + ldsoff);
                g2lds16(wihp + brow0 + k0, Bs + ldsoff);
                g2lds16(wihp + brow1 + k0, Bs + 4096 + ldsoff);
                __syncthreads();

                bf16x8 af[4], bfr[4];
                #pragma unroll
                for (int i = 0; i < 4; ++i) {
                    af[i]  = *(const bf16x8*)(As + (wr*64 + i*16 + (lane & 15))*64 + (lane >> 4)*16);
                    bfr[i] = *(const bf16x8*)(Bs + (wc*64 + i*16 + (lane & 15))*64 + (lane >> 4)*16);
                }
                #pragma unroll
                for (int i = 0; i < 4; ++i)
                    #pragma unroll
                    for (int j = 0; j < 4; ++j)
                        acc[i][j] = __builtin_amdgcn_mfma_f32_16x16x32_bf16(
                            af[i], bfr[j], acc[i][j], 0, 0, 0);
                __syncthreads();
            }

            // epilogue: write-through stores (visible at LLC for consumers)
            #pragma unroll
            for (int j = 0; j < 4; ++j) {
                const int nn = n0 + wc*64 + j*16 + (lane & 15);
                const float bias = bsum[nn];
                #pragma unroll
                for (int i = 0; i < 4; ++i) {
                    #pragma unroll
                    for (int r = 0; r < 4; ++r) {
                        const int mm = m0 + wr*64 + i*16 + ((lane >> 4) << 2) + r;
                        const bf16 o16 = (bf16)(acc[i][j][r] + bias);
                        store2_cc(xgp + (size_t)mm * NG + nn,
                                  (u32)__builtin_bit_cast(unsigned short, o16));
                    }
                }
            }
            WAITVM(0);                 // all this thread's tile stores at LLC
            __syncthreads();           // ...all threads'
            if (tid == 0)
                atomicAdd(&mrowdone[by], 1u);   // device-scope release count
        }
        return;
    }

    // ================= LSTM role (R12 verbatim + xg gating) =================
    char* hstage = smem;                                        // 8 x 2064
    float (*gbuf)[8][136] = reinterpret_cast<float(*)[8][136]>(smem + 16512);

    const int wg = (int)blockIdx.x - 256;
    const int hg = wg & 31;
    const int bg = wg >> 5;

    // W fragments -> 256 regs/lane (64 x bf16x8), coalesced 16B loads
    bf16x8 wreg[64];
    {
        const bf16* wb = wfrag + ((size_t)(hg * 4 + wv) * 4096 + lane) * 8;
        #pragma unroll
        for (int f = 0; f < 64; ++f)
            wreg[f] = *(const bf16x8*)(wb + (size_t)f * 512);
    }

    const int frow  = lane & 15;
    const int b_el  = tid >> 5;                       // 0..7
    const int j_el  = tid & 31;                       // 0..31
    const int hid   = hg * 32 + j_el;

    const int goff = (lane >> 3) * 2048 + wv * 512 + (lane & 7) * 16;  // global
    const int woff = (lane >> 3) * 2064 + wv * 512 + (lane & 7) * 16;  // LDS
    const int rbase = frow & 7;
    const int cbase = rbase * 2064 + wv * 512 + (lane >> 4) * 16;

    const u32* pollpA = flags + ((bg * 32 + wv * 8 + (lane & 3)) << 4);
    const u32* pollpB = flags + ((bg * 32 + wv * 8 + 4 + (lane & 3)) << 4);
    u32* myflag       = flags + ((bg * 32 + hg) << 4);

    float c = 0.f;

    // prologue: wait for GEMM M-row 0 (timesteps 0,1), then prefetch xg[0]
    while (__hip_atomic_load(&mrowdone[0], __ATOMIC_RELAXED,
                             __HIP_MEMORY_SCOPE_AGENT) < 32u)
        __builtin_amdgcn_s_sleep(8);
    u32x2 xr = load8_cc(xgp + (size_t)(bg * 8 + b_el) * NG + hid * 4);

    #pragma unroll 1
    for (int step = 0; step < T_STEPS; ++step) {
        // A1: poll first 4 producers AND xg-readiness of the prefetch target
        const int nx  = (step + 1 < T_STEPS) ? step + 1 : step;
        const u32* xrdy = mrowdone + (nx >> 1);
        for (;;) {
            u32 f = __hip_atomic_load(pollpA, __ATOMIC_RELAXED,
                                      __HIP_MEMORY_SCOPE_AGENT);
            u32 gr = __hip_atomic_load(xrdy, __ATOMIC_RELAXED,
                                       __HIP_MEMORY_SCOPE_AGENT);
            if (__all((int)(f >= (u32)step && gr >= 32u))) break;
            __builtin_amdgcn_s_sleep(1);
        }

        // B1: issue chunks 0,1 (half1)
        const char* hbp = (const char*)(hbuf + (step & 1) * (BATCH * HID)
                                             + (size_t)(bg * 8) * HID);
        u32x4 s0 = load16_cc(hbp + goff);
        u32x4 s1 = load16_cc(hbp + goff + 128);

        // A2: poll last 4 producers; its vmcnt(0) drains s0,s1 during the wait
        while (__hip_atomic_load(pollpB, __ATOMIC_RELAXED,
                                 __HIP_MEMORY_SCOPE_AGENT) < (u32)step)
            __builtin_amdgcn_s_sleep(1);

        // B2: issue chunks 2,3
        u32x4 s2 = load16_cc(hbp + goff + 256);
        u32x4 s3 = load16_cc(hbp + goff + 384);

        // C1: stage + compute half1 (s0,s1 already drained by poll A2)
        *(u32x4*)(hstage + woff)       = s0;
        *(u32x4*)(hstage + woff + 128) = s1;
        f32x4 acc[8] = {};
        #pragma unroll
        for (int kk = 0; kk < 4; ++kk) {
            bf16x8 a = *(const bf16x8*)(hstage + cbase + kk * 64);
            #pragma unroll
            for (int n = 0; n < 8; ++n)
                acc[n] = __builtin_amdgcn_mfma_f32_16x16x32_bf16(
                    a, wreg[kk * 8 + n], acc[n], 0, 0, 0);
        }

        // C2: chunks 2,3 landed under MFMA half1
        WAITVM(0);
        __builtin_amdgcn_sched_barrier(0);
        *(u32x4*)(hstage + woff + 256) = s2;
        *(u32x4*)(hstage + woff + 384) = s3;
        #pragma unroll
        for (int kk = 4; kk < 8; ++kk) {
            bf16x8 a = *(const bf16x8*)(hstage + cbase + kk * 64);
            #pragma unroll
            for (int n = 0; n < 8; ++n)
                acc[n] = __builtin_amdgcn_mfma_f32_16x16x32_bf16(
                    a, wreg[kk * 8 + n], acc[n], 0, 0, 0);
        }

        // D: cross-wave reduce staging (valid batch rows live in lanes 0..31)
        if (lane < 32) {
            const int q = lane >> 4;
            #pragma unroll
            for (int n = 0; n < 8; ++n)
                #pragma unroll
                for (int r = 0; r < 4; ++r)
                    gbuf[wv][q * 4 + r][n * 16 + frow] = acc[n][r];
        }
        __syncthreads();

        // E: elementwise; h-store FIRST, then out/xg (younger); WAITVM(2)
        // acks exactly the h-store -> flag publishes without HBM-ack wait.
        bf16x4 xv = __builtin_bit_cast(bf16x4, xr);
        float P[4];
        #pragma unroll
        for (int g = 0; g < 4; ++g)
            P[g] = gbuf[0][b_el][j_el * 4 + g] + gbuf[1][b_el][j_el * 4 + g]
                 + gbuf[2][b_el][j_el * 4 + g] + gbuf[3][b_el][j_el * 4 + g]
                 + (float)xv[g];
        const float ig = fsigmoid(P[0]);
        const float fg = fsigmoid(P[1]);
        const float gg = ftanh_(P[2]);
        const float og = fsigmoid(P[3]);
        c = fg * c + ig * gg;
        const float hv = og * ftanh_(c);

        const bf16 h16 = (bf16)hv;
        store2_cc(hbuf + ((step & 1) ^ 1) * (BATCH * HID)
                       + (size_t)(bg * 8 + b_el) * HID + hid,
                  (u32)__builtin_bit_cast(unsigned short, h16));       // o1
        store4_f32(out + (size_t)(step * BATCH + bg * 8 + b_el) * HID + hid, hv); // o2
        xr = load8_cc(xgp + ((size_t)(nx * BATCH) + bg * 8 + b_el) * NG
                          + hid * 4);                                   // o3
        WAITVM(2);                        // h-store (oldest) acked at LLC
        __builtin_amdgcn_sched_barrier(0);
        __syncthreads();                  // all waves of this WG acked
        if (tid == 0)
            __hip_atomic_store(myflag, (u32)(step + 1),
                               __ATOMIC_RELAXED, __HIP_MEMORY_SCOPE_AGENT);
    }
}

// ---------------------------------------------------------------------------
extern "C" void kernel_launch(void* const* d_in, const int* in_sizes, int n_in,
                              void* d_out, int out_size, void* d_ws, size_t ws_size,
                              hipStream_t stream) {
    const float* x   = (const float*)d_in[0];   // [512,64,1024]
    const float* wih = (const float*)d_in[1];   // [4096,1024]
    const float* whh = (const float*)d_in[2];   // [4096,1024]
    const float* bih = (const float*)d_in[3];   // [4096]
    const float* bhh = (const float*)d_in[4];   // [4096]
    float* out = (float*)d_out;                 // [512,64,1024]

    char* ws = (char*)d_ws;
    size_t off = 0;
    bf16* xgp   = (bf16*)(ws + off); off += (size_t)MROWS * NG * 2;      // 256 MB
    bf16* xb    = (bf16*)(ws + off); off += (size_t)MROWS * DIM * 2;     //  64 MB
    bf16* wihp  = (bf16*)(ws + off); off += (size_t)NG * DIM * 2;        //   8 MB
    bf16* wfrag = (bf16*)(ws + off); off += (size_t)NG * HID * 2;        //   8 MB
    float* bsum = (float*)(ws + off); off += (size_t)NG * 4;             //  16 KB
    bf16* hbuf  = (bf16*)(ws + off); off += (size_t)2 * BATCH * HID * 2; // 256 KB
    u32* flags  = (u32*)(ws + off); off += 256 * 16 * 4;                 //  16 KB
    u32* mrowdone = (u32*)(ws + off); off += 256 * 4;                    //   1 KB
    (void)ws_size; (void)in_sizes; (void)n_in; (void)out_size;

    prep_kernel<<<2048, 256, 0, stream>>>(x, wih, whh, bih, bhh,
                                          xb, wihp, wfrag, bsum, hbuf, flags,
                                          mrowdone);
    fused_kernel<<<512, 256, 0, stream>>>(xb, wihp, bsum, xgp, wfrag,
                                          hbuf, flags, mrowdone, out);
}

// Round 14
// 2119.404 us; speedup vs baseline: 1.5330x; 1.5330x over previous
//
#include <hip/hip_runtime.h>
#include <hip/hip_bf16.h>
#include <stdint.h>

// LSTM: T=512, B=64, D=1024, H=1024, gates order i,f,g,o
#define T_STEPS 512
#define BATCH   64
#define DIM     1024
#define HID     1024
#define NG      4096                 // 4*HID
#define MROWS   (T_STEPS * BATCH)    // 32768

typedef __bf16 bf16;
typedef __bf16 bf16x4 __attribute__((ext_vector_type(4)));
typedef __bf16 bf16x8 __attribute__((ext_vector_type(8)));
typedef float  f32x4  __attribute__((ext_vector_type(4)));
typedef unsigned int u32;
typedef u32 u32x2 __attribute__((ext_vector_type(2)));
typedef u32 u32x4 __attribute__((ext_vector_type(4)));

__device__ __forceinline__ void g2lds16(const void* g, void* l) {
    __builtin_amdgcn_global_load_lds(
        (const __attribute__((address_space(1))) void*)g,
        (__attribute__((address_space(3))) void*)l, 16, 0, 0);
}

__device__ __forceinline__ float fsigmoid(float x) {
    return 1.0f / (1.0f + __expf(-x));   // safe at +-inf
}
__device__ __forceinline__ float ftanh_(float x) {
    return 1.0f - 2.0f / (__expf(2.0f * x) + 1.0f);   // safe at +-inf
}

// ---- LLC-coherent (bypass L1+L2) ops: proven R2-R12 ----
__device__ __forceinline__ u32x4 load16_cc(const void* p) {
    u32x4 r;
    asm volatile("global_load_dwordx4 %0, %1, off sc0 sc1" : "=v"(r) : "v"(p) : "memory");
    return r;
}
__device__ __forceinline__ void store2_cc(void* p, u32 v) {
    asm volatile("global_store_short %0, %1, off sc0 sc1" :: "v"(p), "v"(v) : "memory");
}
__device__ __forceinline__ u32x2 load8_cached(const void* p) {
    u32x2 r;
    asm volatile("global_load_dwordx2 %0, %1, off" : "=v"(r) : "v"(p) : "memory");
    return r;
}
__device__ __forceinline__ void store4_f32(float* p, float v) {
    asm volatile("global_store_dword %0, %1, off" :: "v"(p), "v"(v) : "memory");
}
#define WAITVM(n) asm volatile("s_waitcnt vmcnt(" #n ")" ::: "memory")

// ---------------------------------------------------------------------------
// prep: fp32->bf16 conversions, W_ih column-permute (n' = (n&1023)*4 + (n>>10)),
// W_hh scatter into MFMA-fragment order (wfrag), bias sum (permuted),
// zero h0 buffer and PER-WAVE barrier flags (re-zeroed every launch).
// ---------------------------------------------------------------------------
__global__ __launch_bounds__(256) void prep_kernel(
    const float* __restrict__ x,   const float* __restrict__ wih,
    const float* __restrict__ whh, const float* __restrict__ bih,
    const float* __restrict__ bhh,
    bf16* __restrict__ xb, bf16* __restrict__ wihp, bf16* __restrict__ wfrag,
    float* __restrict__ bsump, bf16* __restrict__ hbuf, u32* __restrict__ flags)
{
    const int nt  = gridDim.x * blockDim.x;
    const int gid = blockIdx.x * blockDim.x + threadIdx.x;

    for (int i = gid; i < MROWS * DIM / 4; i += nt) {
        f32x4 v = *(const f32x4*)(x + (size_t)i * 4);
        bf16x4 o = {(bf16)v[0], (bf16)v[1], (bf16)v[2], (bf16)v[3]};
        *(bf16x4*)(xb + (size_t)i * 4) = o;
    }
    for (int i = gid; i < NG * (DIM / 4); i += nt) {
        const int n = i >> 8, c4 = (i & 255) * 4;
        f32x4 v = *(const f32x4*)(wih + (size_t)n * DIM + c4);
        bf16x4 o = {(bf16)v[0], (bf16)v[1], (bf16)v[2], (bf16)v[3]};
        const int np = ((n & 1023) << 2) | (n >> 10);
        *(bf16x4*)(wihp + (size_t)np * DIM + c4) = o;
    }
    // wfrag: element i = ((hg*4 + wv)*64 + f)*64 + lane, f = kk*8+n;
    // grow = (lane&3)*1024 + hg*32 + n*4 + ((lane&15)>>2), k0 = wv*256+kk*32+(lane>>4)*8
    for (int i = gid; i < NG * HID / 8; i += nt) {
        const int lane = i & 63;
        const int f    = (i >> 6) & 63;
        const int wv   = (i >> 12) & 3;
        const int hg   = i >> 14;
        const int n = f & 7, kk = f >> 3;
        const int grow = (lane & 3) * 1024 + hg * 32 + n * 4 + ((lane & 15) >> 2);
        const int k0   = wv * 256 + kk * 32 + (lane >> 4) * 8;
        f32x4 v0 = *(const f32x4*)(whh + (size_t)grow * HID + k0);
        f32x4 v1 = *(const f32x4*)(whh + (size_t)grow * HID + k0 + 4);
        bf16x8 o = {(bf16)v0[0], (bf16)v0[1], (bf16)v0[2], (bf16)v0[3],
                    (bf16)v1[0], (bf16)v1[1], (bf16)v1[2], (bf16)v1[3]};
        *(bf16x8*)(wfrag + (size_t)i * 8) = o;
    }
    for (int i = gid; i < NG; i += nt)
        bsump[((i & 1023) << 2) | (i >> 10)] = bih[i] + bhh[i];
    for (int i = gid; i < BATCH * HID / 4; i += nt) {
        bf16x4 z = {(bf16)0.f, (bf16)0.f, (bf16)0.f, (bf16)0.f};
        *(bf16x4*)(hbuf + (size_t)i * 4) = z;   // h[buf 0] = 0
    }
    for (int i = gid; i < 256 * 4 * 16; i += nt)
        flags[i] = 0u;
}

// ---------------------------------------------------------------------------
// xg GEMM: C[32768,4096] = xb[32768,1024] @ wihp^T + bsump, bf16 out.
// Default block mapping (R10/R12 proven; R11's XCD swizzle regressed).
// ---------------------------------------------------------------------------
__global__ __launch_bounds__(256) void gemm_kernel(
    const bf16* __restrict__ A, const bf16* __restrict__ B,
    const float* __restrict__ bsum, bf16* __restrict__ xgp)
{
    __shared__ char lds[16384];
    char* As = lds;
    char* Bs = lds + 8192;

    const int tid  = threadIdx.x;
    const int lane = tid & 63;
    const int wv   = tid >> 6;
    const int wr   = wv >> 1, wc = wv & 1;
    const int bx   = blockIdx.x & 31;   // N tile
    const int by   = blockIdx.x >> 5;   // M tile
    const int m0   = by * 128, n0 = bx * 128;

    f32x4 acc[4][4] = {};

    const int r4 = tid >> 2;
    const int c8 = (tid & 3) * 8;
    const size_t arow0 = (size_t)(m0 +      r4) * DIM + c8;
    const size_t arow1 = (size_t)(m0 + 64 + r4) * DIM + c8;
    const size_t brow0 = (size_t)(n0 +      r4) * DIM + c8;
    const size_t brow1 = (size_t)(n0 + 64 + r4) * DIM + c8;
    const int ldsoff = tid * 16;

    for (int k0 = 0; k0 < DIM; k0 += 32) {
        g2lds16(A + arow0 + k0, As + ldsoff);
        g2lds16(A + arow1 + k0, As + 4096 + ldsoff);
        g2lds16(B + brow0 + k0, Bs + ldsoff);
        g2lds16(B + brow1 + k0, Bs + 4096 + ldsoff);
        __syncthreads();

        bf16x8 af[4], bfr[4];
        #pragma unroll
        for (int i = 0; i < 4; ++i) {
            af[i]  = *(const bf16x8*)(As + (wr*64 + i*16 + (lane & 15))*64 + (lane >> 4)*16);
            bfr[i] = *(const bf16x8*)(Bs + (wc*64 + i*16 + (lane & 15))*64 + (lane >> 4)*16);
        }
        #pragma unroll
        for (int i = 0; i < 4; ++i)
            #pragma unroll
            for (int j = 0; j < 4; ++j)
                acc[i][j] = __builtin_amdgcn_mfma_f32_16x16x32_bf16(
                    af[i], bfr[j], acc[i][j], 0, 0, 0);
        __syncthreads();
    }

    #pragma unroll
    for (int j = 0; j < 4; ++j) {
        const int nn = n0 + wc*64 + j*16 + (lane & 15);
        const float bias = bsum[nn];
        #pragma unroll
        for (int i = 0; i < 4; ++i) {
            #pragma unroll
            for (int r = 0; r < 4; ++r) {
                const int mm = m0 + wr*64 + i*16 + ((lane >> 4) << 2) + r;
                xgp[(size_t)mm * NG + nn] = (bf16)(acc[i][j][r] + bias);
            }
        }
    }
}

// ---------------------------------------------------------------------------
// Persistent recurrent kernel — R12 structure with two refinements:
// 1) PER-WAVE flags (R9-proven correctness): producer wave q publishes its
//    own flag after its own WAITVM(2) h-store ack — the E-phase syncthreads
//    is deleted. gbuf is parity-doubled (wave skew without E-sync; the
//    D(t+1)-syncthreads joins all waves' A(t+1) polls whose union covers all
//    128 bg-flags >= t+1 => overwrite of h[t]-buffer is safe; flag(X,q)>=t+1
//    implies X passed D(t)-sync, i.e. ALL X's waves finished reading h[t]).
// 2) E-phase gbuf reads as ds_read_b128 (4 contiguous floats per wave-buf):
//    4 reads x 4-way conflict instead of 16 scalar reads x 8-way — removes
//    the dominant SQ_LDS_BANK_CONFLICT term (256 cy/WG/step in R12).
// Everything else (split poll, chunked staging pipeline, E-tail issue
// order) is R12 verbatim.
// ---------------------------------------------------------------------------
__global__ __launch_bounds__(256, 1) void lstm_kernel(
    const bf16* __restrict__ xgp, const bf16* __restrict__ wfrag,
    bf16* __restrict__ hbuf, u32* __restrict__ flags, float* __restrict__ out)
{
    __shared__ char  hstage[8 * 2064];     // h[8 rows][1024 k] bf16, pitch 2064
    __shared__ float gbuf[2][4][8][136];   // [parity][wave][batch row][gate col]

    const int tid  = threadIdx.x;
    const int lane = tid & 63;
    const int wv   = tid >> 6;
    const int wg   = blockIdx.x;
    const int hg   = wg & 31;
    const int bg   = wg >> 5;

    // W fragments -> 256 regs/lane (64 x bf16x8), coalesced 16B loads
    bf16x8 wreg[64];
    {
        const bf16* wb = wfrag + ((size_t)(hg * 4 + wv) * 4096 + lane) * 8;
        #pragma unroll
        for (int f = 0; f < 64; ++f)
            wreg[f] = *(const bf16x8*)(wb + (size_t)f * 512);
    }

    const int frow  = lane & 15;
    const int b_el  = tid >> 5;                       // 0..7
    const int j_el  = tid & 31;                       // 0..31
    const int hid   = hg * 32 + j_el;

    // staging: chunk c = k-quarter c*64..+64 x rows 0..7.
    const int goff = (lane >> 3) * 2048 + wv * 512 + (lane & 7) * 16;  // global
    const int woff = (lane >> 3) * 2064 + wv * 512 + (lane & 7) * 16;  // LDS
    const int rbase = frow & 7;
    const int cbase = rbase * 2064 + wv * 512 + (lane >> 4) * 16;

    // per-wave flags: idx = ((bg*32 + hg)*4 + wave) * 16 (64B spacing).
    // A1 polls producers wv*8+0..3 (x 4 waves, 16 flags on lanes 0..15 rep.);
    // A2 polls producers wv*8+4..7.
    const u32* pollpA = flags
        + ((size_t)((bg * 32 + wv * 8 +     (lane & 3)) * 4 + ((lane >> 2) & 3)) << 4);
    const u32* pollpB = flags
        + ((size_t)((bg * 32 + wv * 8 + 4 + (lane & 3)) * 4 + ((lane >> 2) & 3)) << 4);
    u32* myflag = flags + ((size_t)((bg * 32 + hg) * 4 + wv) << 4);

    float c = 0.f;
    u32x2 xr = load8_cached(xgp + (size_t)(bg * 8 + b_el) * NG + hid * 4);

    #pragma unroll 1
    for (int step = 0; step < T_STEPS; ++step) {
        const int pp = step & 1;

        // A1: poll first 4 producers (all 4 waves each). The atomic load's
        // implicit vmcnt(0) also drains prev-step out/xg acks (idle time).
        while (__hip_atomic_load(pollpA, __ATOMIC_RELAXED,
                                 __HIP_MEMORY_SCOPE_AGENT) < (u32)step)
            __builtin_amdgcn_s_sleep(1);

        // B1: issue chunks 0,1 (half1)
        const char* hbp = (const char*)(hbuf + (step & 1) * (BATCH * HID)
                                             + (size_t)(bg * 8) * HID);
        u32x4 s0 = load16_cc(hbp + goff);
        u32x4 s1 = load16_cc(hbp + goff + 128);

        // A2: poll last 4 producers; its vmcnt(0) drains s0,s1 during the wait
        while (__hip_atomic_load(pollpB, __ATOMIC_RELAXED,
                                 __HIP_MEMORY_SCOPE_AGENT) < (u32)step)
            __builtin_amdgcn_s_sleep(1);

        // B2: issue chunks 2,3
        u32x4 s2 = load16_cc(hbp + goff + 256);
        u32x4 s3 = load16_cc(hbp + goff + 384);

        // C1: stage + compute half1 (s0,s1 already drained by poll A2)
        *(u32x4*)(hstage + woff)       = s0;
        *(u32x4*)(hstage + woff + 128) = s1;
        f32x4 acc[8] = {};
        #pragma unroll
        for (int kk = 0; kk < 4; ++kk) {
            bf16x8 a = *(const bf16x8*)(hstage + cbase + kk * 64);
            #pragma unroll
            for (int n = 0; n < 8; ++n)
                acc[n] = __builtin_amdgcn_mfma_f32_16x16x32_bf16(
                    a, wreg[kk * 8 + n], acc[n], 0, 0, 0);
        }

        // C2: chunks 2,3 landed under MFMA half1
        WAITVM(0);
        __builtin_amdgcn_sched_barrier(0);
        *(u32x4*)(hstage + woff + 256) = s2;
        *(u32x4*)(hstage + woff + 384) = s3;
        #pragma unroll
        for (int kk = 4; kk < 8; ++kk) {
            bf16x8 a = *(const bf16x8*)(hstage + cbase + kk * 64);
            #pragma unroll
            for (int n = 0; n < 8; ++n)
                acc[n] = __builtin_amdgcn_mfma_f32_16x16x32_bf16(
                    a, wreg[kk * 8 + n], acc[n], 0, 0, 0);
        }

        // D: cross-wave reduce staging (parity buffer pp), one syncthreads
        if (lane < 32) {
            const int q = lane >> 4;
            #pragma unroll
            for (int n = 0; n < 8; ++n)
                #pragma unroll
                for (int r = 0; r < 4; ++r)
                    gbuf[pp][wv][q * 4 + r][n * 16 + frow] = acc[n][r];
        }
        __syncthreads();

        // E: elementwise; gbuf via b128 (4 contiguous floats per wave-buf);
        // h-store FIRST, then out/xg (younger); WAITVM(2) acks exactly the
        // h-store; PER-WAVE flag — no E-syncthreads.
        f32x4 pv0 = *(const f32x4*)&gbuf[pp][0][b_el][j_el * 4];
        f32x4 pv1 = *(const f32x4*)&gbuf[pp][1][b_el][j_el * 4];
        f32x4 pv2 = *(const f32x4*)&gbuf[pp][2][b_el][j_el * 4];
        f32x4 pv3 = *(const f32x4*)&gbuf[pp][3][b_el][j_el * 4];
        bf16x4 xv = __builtin_bit_cast(bf16x4, xr);
        float P[4];
        #pragma unroll
        for (int g = 0; g < 4; ++g)
            P[g] = pv0[g] + pv1[g] + pv2[g] + pv3[g] + (float)xv[g];
        const float ig = fsigmoid(P[0]);
        const float fg = fsigmoid(P[1]);
        const float gg = ftanh_(P[2]);
        const float og = fsigmoid(P[3]);
        c = fg * c + ig * gg;
        const float hv = og * ftanh_(c);

        const bf16 h16 = (bf16)hv;
        store2_cc(hbuf + ((step & 1) ^ 1) * (BATCH * HID)
                       + (size_t)(bg * 8 + b_el) * HID + hid,
                  (u32)__builtin_bit_cast(unsigned short, h16));       // o1
        store4_f32(out + (size_t)(step * BATCH + bg * 8 + b_el) * HID + hid, hv); // o2
        const int nx = (step + 1 < T_STEPS) ? step + 1 : step;
        xr = load8_cached(xgp + ((size_t)(nx * BATCH) + bg * 8 + b_el) * NG
                              + hid * 4);                               // o3
        WAITVM(2);                        // h-store (oldest) acked at LLC
        __builtin_amdgcn_sched_barrier(0);
        if (lane == 0)
            __hip_atomic_store(myflag, (u32)(step + 1),
                               __ATOMIC_RELAXED, __HIP_MEMORY_SCOPE_AGENT);
    }
}

// ---------------------------------------------------------------------------
extern "C" void kernel_launch(void* const* d_in, const int* in_sizes, int n_in,
                              void* d_out, int out_size, void* d_ws, size_t ws_size,
                              hipStream_t stream) {
    const float* x   = (const float*)d_in[0];   // [512,64,1024]
    const float* wih = (const float*)d_in[1];   // [4096,1024]
    const float* whh = (const float*)d_in[2];   // [4096,1024]
    const float* bih = (const float*)d_in[3];   // [4096]
    const float* bhh = (const float*)d_in[4];   // [4096]
    float* out = (float*)d_out;                 // [512,64,1024]

    char* ws = (char*)d_ws;
    size_t off = 0;
    bf16* xgp   = (bf16*)(ws + off); off += (size_t)MROWS * NG * 2;      // 256 MB
    bf16* xb    = (bf16*)(ws + off); off += (size_t)MROWS * DIM * 2;     //  64 MB
    bf16* wihp  = (bf16*)(ws + off); off += (size_t)NG * DIM * 2;        //   8 MB
    bf16* wfrag = (bf16*)(ws + off); off += (size_t)NG * HID * 2;        //   8 MB
    float* bsum = (float*)(ws + off); off += (size_t)NG * 4;             //  16 KB
    bf16* hbuf  = (bf16*)(ws + off); off += (size_t)2 * BATCH * HID * 2; // 256 KB
    u32* flags  = (u32*)(ws + off); off += 256 * 4 * 16 * 4;             //  64 KB
    (void)ws_size; (void)in_sizes; (void)n_in; (void)out_size;

    prep_kernel<<<2048, 256, 0, stream>>>(x, wih, whh, bih, bhh,
                                          xb, wihp, wfrag, bsum, hbuf, flags);
    gemm_kernel<<<8192, 256, 0, stream>>>(xb, wihp, bsum, xgp);
    lstm_kernel<<<256, 256, 0, stream>>>(xgp, wfrag, hbuf, flags, out);
}

// Round 16
// 1896.979 us; speedup vs baseline: 1.7128x; 1.1173x over previous
//
#include <hip/hip_runtime.h>
#include <hip/hip_bf16.h>
#include <stdint.h>

// LSTM: T=512, B=64, D=1024, H=1024, gates order i,f,g,o
#define T_STEPS 512
#define BATCH   64
#define DIM     1024
#define HID     1024
#define NG      4096                 // 4*HID
#define MROWS   (T_STEPS * BATCH)    // 32768

typedef __bf16 bf16;
typedef __bf16 bf16x4 __attribute__((ext_vector_type(4)));
typedef __bf16 bf16x8 __attribute__((ext_vector_type(8)));
typedef float  f32x4  __attribute__((ext_vector_type(4)));
typedef unsigned int u32;
typedef u32 u32x2 __attribute__((ext_vector_type(2)));
typedef u32 u32x4 __attribute__((ext_vector_type(4)));

__device__ __forceinline__ void g2lds16(const void* g, void* l) {
    __builtin_amdgcn_global_load_lds(
        (const __attribute__((address_space(1))) void*)g,
        (__attribute__((address_space(3))) void*)l, 16, 0, 0);
}

__device__ __forceinline__ float fsigmoid(float x) {
    return 1.0f / (1.0f + __expf(-x));   // safe at +-inf
}
__device__ __forceinline__ float ftanh_(float x) {
    return 1.0f - 2.0f / (__expf(2.0f * x) + 1.0f);   // safe at +-inf
}

// ---- LLC-coherent (bypass L1+L2) ops: proven in R2/R3/R8/R10/R11/R12 ----
__device__ __forceinline__ u32x4 load16_cc(const void* p) {
    u32x4 r;
    asm volatile("global_load_dwordx4 %0, %1, off sc0 sc1" : "=v"(r) : "v"(p) : "memory");
    return r;
}
__device__ __forceinline__ void store2_cc(void* p, u32 v) {
    asm volatile("global_store_short %0, %1, off sc0 sc1" :: "v"(p), "v"(v) : "memory");
}
__device__ __forceinline__ u32x2 load8_cached(const void* p) {
    u32x2 r;
    asm volatile("global_load_dwordx2 %0, %1, off" : "=v"(r) : "v"(p) : "memory");
    return r;
}
__device__ __forceinline__ void store4_f32(float* p, float v) {
    asm volatile("global_store_dword %0, %1, off" :: "v"(p), "v"(v) : "memory");
}
#define WAITVM(n) asm volatile("s_waitcnt vmcnt(" #n ")" ::: "memory")

// ---------------------------------------------------------------------------
// prep: fp32->bf16 conversions, W_ih column-permute (n' = (n&1023)*4 + (n>>10)),
// W_hh scatter into MFMA-fragment order (wfrag), bias sum (permuted),
// zero h0 buffer and barrier flags (re-zeroed every launch => replay-safe).
// ---------------------------------------------------------------------------
__global__ __launch_bounds__(256) void prep_kernel(
    const float* __restrict__ x,   const float* __restrict__ wih,
    const float* __restrict__ whh, const float* __restrict__ bih,
    const float* __restrict__ bhh,
    bf16* __restrict__ xb, bf16* __restrict__ wihp, bf16* __restrict__ wfrag,
    float* __restrict__ bsump, bf16* __restrict__ hbuf, u32* __restrict__ flags)
{
    const int nt  = gridDim.x * blockDim.x;
    const int gid = blockIdx.x * blockDim.x + threadIdx.x;

    for (int i = gid; i < MROWS * DIM / 4; i += nt) {
        f32x4 v = *(const f32x4*)(x + (size_t)i * 4);
        bf16x4 o = {(bf16)v[0], (bf16)v[1], (bf16)v[2], (bf16)v[3]};
        *(bf16x4*)(xb + (size_t)i * 4) = o;
    }
    for (int i = gid; i < NG * (DIM / 4); i += nt) {
        const int n = i >> 8, c4 = (i & 255) * 4;
        f32x4 v = *(const f32x4*)(wih + (size_t)n * DIM + c4);
        bf16x4 o = {(bf16)v[0], (bf16)v[1], (bf16)v[2], (bf16)v[3]};
        const int np = ((n & 1023) << 2) | (n >> 10);
        *(bf16x4*)(wihp + (size_t)np * DIM + c4) = o;
    }
    // wfrag: element i = ((hg*4 + wv)*64 + f)*64 + lane, f = kk*8+n;
    // grow = (lane&3)*1024 + hg*32 + n*4 + ((lane&15)>>2), k0 = wv*256+kk*32+(lane>>4)*8
    for (int i = gid; i < NG * HID / 8; i += nt) {
        const int lane = i & 63;
        const int f    = (i >> 6) & 63;
        const int wv   = (i >> 12) & 3;
        const int hg   = i >> 14;
        const int n = f & 7, kk = f >> 3;
        const int grow = (lane & 3) * 1024 + hg * 32 + n * 4 + ((lane & 15) >> 2);
        const int k0   = wv * 256 + kk * 32 + (lane >> 4) * 8;
        f32x4 v0 = *(const f32x4*)(whh + (size_t)grow * HID + k0);
        f32x4 v1 = *(const f32x4*)(whh + (size_t)grow * HID + k0 + 4);
        bf16x8 o = {(bf16)v0[0], (bf16)v0[1], (bf16)v0[2], (bf16)v0[3],
                    (bf16)v1[0], (bf16)v1[1], (bf16)v1[2], (bf16)v1[3]};
        *(bf16x8*)(wfrag + (size_t)i * 8) = o;
    }
    for (int i = gid; i < NG; i += nt)
        bsump[((i & 1023) << 2) | (i >> 10)] = bih[i] + bhh[i];
    for (int i = gid; i < BATCH * HID / 4; i += nt) {
        bf16x4 z = {(bf16)0.f, (bf16)0.f, (bf16)0.f, (bf16)0.f};
        *(bf16x4*)(hbuf + (size_t)i * 4) = z;   // h[buf 0] = 0
    }
    for (int i = gid; i < 256 * 16; i += nt)
        flags[i] = 0u;
}

// ---------------------------------------------------------------------------
// xg GEMM: C[32768,4096] = xb[32768,1024] @ wihp^T + bsump, bf16 out.
// Default block mapping (R10/R12 proven; R11's XCD swizzle regressed).
// ---------------------------------------------------------------------------
__global__ __launch_bounds__(256) void gemm_kernel(
    const bf16* __restrict__ A, const bf16* __restrict__ B,
    const float* __restrict__ bsum, bf16* __restrict__ xgp)
{
    __shared__ char lds[16384];
    char* As = lds;
    char* Bs = lds + 8192;

    const int tid  = threadIdx.x;
    const int lane = tid & 63;
    const int wv   = tid >> 6;
    const int wr   = wv >> 1, wc = wv & 1;
    const int bx   = blockIdx.x & 31;   // N tile
    const int by   = blockIdx.x >> 5;   // M tile
    const int m0   = by * 128, n0 = bx * 128;

    f32x4 acc[4][4] = {};

    const int r4 = tid >> 2;
    const int c8 = (tid & 3) * 8;
    const size_t arow0 = (size_t)(m0 +      r4) * DIM + c8;
    const size_t arow1 = (size_t)(m0 + 64 + r4) * DIM + c8;
    const size_t brow0 = (size_t)(n0 +      r4) * DIM + c8;
    const size_t brow1 = (size_t)(n0 + 64 + r4) * DIM + c8;
    const int ldsoff = tid * 16;

    for (int k0 = 0; k0 < DIM; k0 += 32) {
        g2lds16(A + arow0 + k0, As + ldsoff);
        g2lds16(A + arow1 + k0, As + 4096 + ldsoff);
        g2lds16(B + brow0 + k0, Bs + ldsoff);
        g2lds16(B + brow1 + k0, Bs + 4096 + ldsoff);
        __syncthreads();

        bf16x8 af[4], bfr[4];
        #pragma unroll
        for (int i = 0; i < 4; ++i) {
            af[i]  = *(const bf16x8*)(As + (wr*64 + i*16 + (lane & 15))*64 + (lane >> 4)*16);
            bfr[i] = *(const bf16x8*)(Bs + (wc*64 + i*16 + (lane & 15))*64 + (lane >> 4)*16);
        }
        #pragma unroll
        for (int i = 0; i < 4; ++i)
            #pragma unroll
            for (int j = 0; j < 4; ++j)
                acc[i][j] = __builtin_amdgcn_mfma_f32_16x16x32_bf16(
                    af[i], bfr[j], acc[i][j], 0, 0, 0);
        __syncthreads();
    }

    #pragma unroll
    for (int j = 0; j < 4; ++j) {
        const int nn = n0 + wc*64 + j*16 + (lane & 15);
        const float bias = bsum[nn];
        #pragma unroll
        for (int i = 0; i < 4; ++i) {
            #pragma unroll
            for (int r = 0; r < 4; ++r) {
                const int mm = m0 + wr*64 + i*16 + ((lane >> 4) << 2) + r;
                xgp[(size_t)mm * NG + nn] = (bf16)(acc[i][j][r] + bias);
            }
        }
    }
}

// ---------------------------------------------------------------------------
// Persistent recurrent kernel — EXACT R12 source (passed full replay
// validation at 1894.7 us total; lstm 1565 us). R15's f32x4 gbuf-read
// variant caused a post-timing replay divergence and is reverted; this is
// the configuration with the strongest pass evidence. Structure:
//   A1 poll(prod 0..3) -> B1 issue s0,s1 -> A2 poll(4..7) [drains s0,s1]
//   -> B2 issue s2,s3 -> C1 stage+MFMA half1 -> WAITVM(0) -> C2 half2
//   -> D gbuf reduce + sync -> E elementwise (scalar gbuf reads), h-store,
//   out, xg, WAITVM(2) [acks exactly the h-store], sync, tid0 flag.
// ---------------------------------------------------------------------------
__global__ __launch_bounds__(256, 1) void lstm_kernel(
    const bf16* __restrict__ xgp, const bf16* __restrict__ wfrag,
    bf16* __restrict__ hbuf, u32* __restrict__ flags, float* __restrict__ out)
{
    __shared__ char  hstage[8 * 2064];  // h[8 rows][1024 k] bf16, pitch 2064
    __shared__ float gbuf[4][8][136];   // [wave][batch row][gate col]

    const int tid  = threadIdx.x;
    const int lane = tid & 63;
    const int wv   = tid >> 6;
    const int wg   = blockIdx.x;
    const int hg   = wg & 31;
    const int bg   = wg >> 5;

    // W fragments -> 256 regs/lane (64 x bf16x8), coalesced 16B loads
    bf16x8 wreg[64];
    {
        const bf16* wb = wfrag + ((size_t)(hg * 4 + wv) * 4096 + lane) * 8;
        #pragma unroll
        for (int f = 0; f < 64; ++f)
            wreg[f] = *(const bf16x8*)(wb + (size_t)f * 512);
    }

    const int frow  = lane & 15;
    const int b_el  = tid >> 5;                       // 0..7
    const int j_el  = tid & 31;                       // 0..31
    const int hid   = hg * 32 + j_el;

    // staging: chunk c = k-quarter c*64..+64 x rows 0..7.
    const int goff = (lane >> 3) * 2048 + wv * 512 + (lane & 7) * 16;  // global
    const int woff = (lane >> 3) * 2064 + wv * 512 + (lane & 7) * 16;  // LDS
    const int rbase = frow & 7;
    const int cbase = rbase * 2064 + wv * 512 + (lane >> 4) * 16;

    const u32* pollpA = flags + ((bg * 32 + wv * 8 + (lane & 3)) << 4);
    const u32* pollpB = flags + ((bg * 32 + wv * 8 + 4 + (lane & 3)) << 4);
    u32* myflag       = flags + ((bg * 32 + hg) << 4);

    float c = 0.f;
    u32x2 xr = load8_cached(xgp + (size_t)(bg * 8 + b_el) * NG + hid * 4);

    #pragma unroll 1
    for (int step = 0; step < T_STEPS; ++step) {
        // A1: poll this wave's first 4 producers (K-half1 ready).
        // The atomic load's implicit vmcnt(0) also drains prev-step out/xg
        // acks during the spin (idle time).
        while (__hip_atomic_load(pollpA, __ATOMIC_RELAXED,
                                 __HIP_MEMORY_SCOPE_AGENT) < (u32)step)
            __builtin_amdgcn_s_sleep(1);

        // B1: issue chunks 0,1 (half1)
        const char* hbp = (const char*)(hbuf + (step & 1) * (BATCH * HID)
                                             + (size_t)(bg * 8) * HID);
        u32x4 s0 = load16_cc(hbp + goff);
        u32x4 s1 = load16_cc(hbp + goff + 128);

        // A2: poll last 4 producers; its vmcnt(0) drains s0,s1 during the wait
        while (__hip_atomic_load(pollpB, __ATOMIC_RELAXED,
                                 __HIP_MEMORY_SCOPE_AGENT) < (u32)step)
            __builtin_amdgcn_s_sleep(1);

        // B2: issue chunks 2,3
        u32x4 s2 = load16_cc(hbp + goff + 256);
        u32x4 s3 = load16_cc(hbp + goff + 384);

        // C1: stage + compute half1 (s0,s1 already drained by poll A2)
        *(u32x4*)(hstage + woff)       = s0;
        *(u32x4*)(hstage + woff + 128) = s1;
        f32x4 acc[8] = {};
        #pragma unroll
        for (int kk = 0; kk < 4; ++kk) {
            bf16x8 a = *(const bf16x8*)(hstage + cbase + kk * 64);
            #pragma unroll
            for (int n = 0; n < 8; ++n)
                acc[n] = __builtin_amdgcn_mfma_f32_16x16x32_bf16(
                    a, wreg[kk * 8 + n], acc[n], 0, 0, 0);
        }

        // C2: chunks 2,3 landed under MFMA half1
        WAITVM(0);
        __builtin_amdgcn_sched_barrier(0);
        *(u32x4*)(hstage + woff + 256) = s2;
        *(u32x4*)(hstage + woff + 384) = s3;
        #pragma unroll
        for (int kk = 4; kk < 8; ++kk) {
            bf16x8 a = *(const bf16x8*)(hstage + cbase + kk * 64);
            #pragma unroll
            for (int n = 0; n < 8; ++n)
                acc[n] = __builtin_amdgcn_mfma_f32_16x16x32_bf16(
                    a, wreg[kk * 8 + n], acc[n], 0, 0, 0);
        }

        // D: cross-wave reduce staging (valid batch rows live in lanes 0..31)
        if (lane < 32) {
            const int q = lane >> 4;
            #pragma unroll
            for (int n = 0; n < 8; ++n)
                #pragma unroll
                for (int r = 0; r < 4; ++r)
                    gbuf[wv][q * 4 + r][n * 16 + frow] = acc[n][r];
        }
        __syncthreads();

        // E: elementwise; h-store FIRST, then out/xg (younger), WAITVM(2)
        // acks exactly the h-store -> flag publishes without HBM-ack wait.
        bf16x4 xv = __builtin_bit_cast(bf16x4, xr);
        float P[4];
        #pragma unroll
        for (int g = 0; g < 4; ++g)
            P[g] = gbuf[0][b_el][j_el * 4 + g] + gbuf[1][b_el][j_el * 4 + g]
                 + gbuf[2][b_el][j_el * 4 + g] + gbuf[3][b_el][j_el * 4 + g]
                 + (float)xv[g];
        const float ig = fsigmoid(P[0]);
        const float fg = fsigmoid(P[1]);
        const float gg = ftanh_(P[2]);
        const float og = fsigmoid(P[3]);
        c = fg * c + ig * gg;
        const float hv = og * ftanh_(c);

        const bf16 h16 = (bf16)hv;
        store2_cc(hbuf + ((step & 1) ^ 1) * (BATCH * HID)
                       + (size_t)(bg * 8 + b_el) * HID + hid,
                  (u32)__builtin_bit_cast(unsigned short, h16));       // o1
        store4_f32(out + (size_t)(step * BATCH + bg * 8 + b_el) * HID + hid, hv); // o2
        const int nx = (step + 1 < T_STEPS) ? step + 1 : step;
        xr = load8_cached(xgp + ((size_t)(nx * BATCH) + bg * 8 + b_el) * NG
                              + hid * 4);                               // o3
        WAITVM(2);                        // h-store (oldest) acked at LLC
        __builtin_amdgcn_sched_barrier(0);
        __syncthreads();                  // all waves of this WG acked
        if (tid == 0)
            __hip_atomic_store(myflag, (u32)(step + 1),
                               __ATOMIC_RELAXED, __HIP_MEMORY_SCOPE_AGENT);
    }
}

// ---------------------------------------------------------------------------
extern "C" void kernel_launch(void* const* d_in, const int* in_sizes, int n_in,
                              void* d_out, int out_size, void* d_ws, size_t ws_size,
                              hipStream_t stream) {
    const float* x   = (const float*)d_in[0];   // [512,64,1024]
    const float* wih = (const float*)d_in[1];   // [4096,1024]
    const float* whh = (const float*)d_in[2];   // [4096,1024]
    const float* bih = (const float*)d_in[3];   // [4096]
    const float* bhh = (const float*)d_in[4];   // [4096]
    float* out = (float*)d_out;                 // [512,64,1024]

    char* ws = (char*)d_ws;
    size_t off = 0;
    bf16* xgp   = (bf16*)(ws + off); off += (size_t)MROWS * NG * 2;      // 256 MB
    bf16* xb    = (bf16*)(ws + off); off += (size_t)MROWS * DIM * 2;     //  64 MB
    bf16* wihp  = (bf16*)(ws + off); off += (size_t)NG * DIM * 2;        //   8 MB
    bf16* wfrag = (bf16*)(ws + off); off += (size_t)NG * HID * 2;        //   8 MB
    float* bsum = (float*)(ws + off); off += (size_t)NG * 4;             //  16 KB
    bf16* hbuf  = (bf16*)(ws + off); off += (size_t)2 * BATCH * HID * 2; // 256 KB
    u32* flags  = (u32*)(ws + off); off += 256 * 16 * 4;                 //  16 KB
    (void)ws_size; (void)in_sizes; (void)n_in; (void)out_size;

    prep_kernel<<<2048, 256, 0, stream>>>(x, wih, whh, bih, bhh,
                                          xb, wihp, wfrag, bsum, hbuf, flags);
    gemm_kernel<<<8192, 256, 0, stream>>>(xb, wihp, bsum, xgp);
    lstm_kernel<<<256, 256, 0, stream>>>(xgp, wfrag, hbuf, flags, out);
}